// Round 3
// baseline (68.526 us; speedup 1.0000x reference)
//
#include <hip/hip_runtime.h>

// Bilateral blur, fixed shape: x = (B=2, C=4, H=256, W=256) f32.
// kernel_size = 13, sigma_color = sigma_space = 3.0, reflect pad, L1 color dist.
// weight(tap) = exp(-( (sum_c|dv_c|)^2 + dy^2+dx^2 ) / 18) up to a constant
// scale (gaussian normalization) that cancels in sum(p*w)/sum(w).
//
// VALU trick: stage v' = v * S in LDS with S^2 = log2(e)/18, so
//   w = exp2( -( (S*d)^2 + r2' ) ),  r2' = (dy^2+dx^2)*log2(e)/18  (compile-time)
// One fma + one v_exp_f32 (negate folded as input modifier) per tap.
// The uniform S on patches is undone in the final normalize.

#define KS   13
#define PAD  6
#define TILE 16
#define HALO (TILE + KS - 1)   // 28
#define HH   256
#define WW   256
#define CC   4

// S^2 = log2(e)/18 = 0.0801497244938313
#define KLOG   0.0801497244938313
#define SCL    0.2831072843f           // sqrt(KLOG)
#define INV_SCL (1.0f / 0.2831072843f)

__global__ __launch_bounds__(TILE * TILE)
void bilateral_kernel(const float* __restrict__ in, float* __restrict__ out) {
    // channel-interleaved halo tile: [y][x][c], 28*28*4 floats = 12544 B
    __shared__ float smem[HALO * HALO * CC];

    const int tx  = threadIdx.x;
    const int ty  = threadIdx.y;
    const int bx0 = blockIdx.x * TILE;
    const int by0 = blockIdx.y * TILE;
    const int b   = blockIdx.z;
    const float* __restrict__ inb = in + b * (CC * HH * WW);

    // ---- stage halo tile (reflect padding), channel-interleaved, pre-scaled ----
    const int tid = ty * TILE + tx;
    #pragma unroll
    for (int idx = tid; idx < HALO * HALO * CC; idx += TILE * TILE) {
        int c   = idx / (HALO * HALO);
        int rem = idx - c * (HALO * HALO);
        int y   = rem / HALO;
        int x   = rem - y * HALO;
        int gy  = by0 + y - PAD;
        gy = (gy < 0) ? -gy : ((gy >= HH) ? 2 * (HH - 1) - gy : gy);
        int gx  = bx0 + x - PAD;
        gx = (gx < 0) ? -gx : ((gx >= WW) ? 2 * (WW - 1) - gx : gx);
        smem[(y * HALO + x) * CC + c] = inb[(c * HH + gy) * WW + gx] * SCL;
    }
    __syncthreads();

    const float4* __restrict__ sm4 = reinterpret_cast<const float4*>(smem);
    const float4 cv = sm4[(ty + PAD) * HALO + (tx + PAD)];

    float acc0 = 0.f, acc1 = 0.f, acc2 = 0.f, acc3 = 0.f, wsum = 0.f;

    #pragma unroll
    for (int iy = 0; iy < KS; ++iy) {
        #pragma unroll
        for (int ix = 0; ix < KS; ++ix) {
            float4 v = sm4[(ty + iy) * HALO + (tx + ix)];
            // 4 sub + 2 add(|a|,|b|) + 1 add -- abs folds into VOP3 modifiers
            float d = (fabsf(v.x - cv.x) + fabsf(v.y - cv.y))
                    + (fabsf(v.z - cv.z) + fabsf(v.w - cv.w));
            // spatial term pre-scaled by log2(e)/18, compile-time per tap
            const float r2s = (float)(((iy - PAD) * (iy - PAD) +
                                       (ix - PAD) * (ix - PAD)) * KLOG);
            float wgt = __builtin_amdgcn_exp2f(-fmaf(d, d, r2s));
            wsum += wgt;
            acc0 = fmaf(wgt, v.x, acc0);
            acc1 = fmaf(wgt, v.y, acc1);
            acc2 = fmaf(wgt, v.z, acc2);
            acc3 = fmaf(wgt, v.w, acc3);
        }
    }

    // undo the S pre-scale on patches: out = (acc / S) / wsum
    const float inv = INV_SCL / wsum;
    const int gy = by0 + ty;
    const int gx = bx0 + tx;
    float* __restrict__ outb = out + b * (CC * HH * WW);
    outb[(0 * HH + gy) * WW + gx] = acc0 * inv;
    outb[(1 * HH + gy) * WW + gx] = acc1 * inv;
    outb[(2 * HH + gy) * WW + gx] = acc2 * inv;
    outb[(3 * HH + gy) * WW + gx] = acc3 * inv;
}

extern "C" void kernel_launch(void* const* d_in, const int* in_sizes, int n_in,
                              void* d_out, int out_size, void* d_ws, size_t ws_size,
                              hipStream_t stream) {
    const float* x = (const float*)d_in[0];
    float* out = (float*)d_out;
    dim3 grid(WW / TILE, HH / TILE, 2);
    dim3 block(TILE, TILE);
    bilateral_kernel<<<grid, block, 0, stream>>>(x, out);
}

// Round 4
// 68.434 us; speedup vs baseline: 1.0013x; 1.0013x over previous
//
#include <hip/hip_runtime.h>

// Bilateral blur, fixed shape: x = (B=2, C=4, H=256, W=256) f32.
// KS=13, sigma_color = sigma_space = 3.0, reflect pad, L1 color distance.
// w(tap) = exp(-((sum_c|dv|)^2 + dy^2+dx^2)/18) up to a constant that cancels.
// Staged data pre-scaled by S (S^2 = log2e/18) so w = exp2(-(d'^2 + r2')),
// r2' compile-time per tap; one fma + one v_exp_f32 per tap.
//
// This round: tap-parallel split. Block (16,16,4); each z-slice computes a
// ~43-tap partial sum for its pixel; z>0 write 5-float partials to LDS
// (stride 5 dwords -> conflict-free); z==0 reduces + normalizes.
// Raises waves/SIMD from 2 to 4 to hide LDS latency.

#define KS   13
#define PAD  6
#define TILE 16
#define HALO (TILE + KS - 1)   // 28
#define HH   256
#define WW   256
#define CC   4
#define ZS   4
#define NPX  (TILE * TILE)

#define KLOG   0.0801497244938313      // log2(e)/18
#define SCL    0.2831072843f           // sqrt(KLOG)
#define INV_SCL (1.0f / 0.2831072843f)

template <int J0, int J1>
__device__ __forceinline__ void taps(const float4* __restrict__ sm4,
                                     int ty, int tx, float4 cv,
                                     float& a0, float& a1, float& a2,
                                     float& a3, float& w) {
    #pragma unroll
    for (int j = J0; j < J1; ++j) {
        const int iy = j / KS;
        const int ix = j % KS;
        float4 v = sm4[(ty + iy) * HALO + (tx + ix)];
        float d = (fabsf(v.x - cv.x) + fabsf(v.y - cv.y))
                + (fabsf(v.z - cv.z) + fabsf(v.w - cv.w));
        const float r2s = (float)(((iy - PAD) * (iy - PAD) +
                                   (ix - PAD) * (ix - PAD)) * KLOG);
        float wg = __builtin_amdgcn_exp2f(-fmaf(d, d, r2s));
        w += wg;
        a0 = fmaf(wg, v.x, a0);
        a1 = fmaf(wg, v.y, a1);
        a2 = fmaf(wg, v.z, a2);
        a3 = fmaf(wg, v.w, a3);
    }
}

__global__ __launch_bounds__(NPX * ZS)
void bilateral_kernel(const float* __restrict__ in, float* __restrict__ out) {
    // channel-interleaved halo tile: [y][x][c], 28*28*4 floats = 12544 B
    __shared__ float smem[HALO * HALO * CC];
    // partial sums from z=1..3: [z-1][pixel][5], stride 5 dwords (conflict-free)
    __shared__ float part[(ZS - 1) * NPX * 5];

    const int tx  = threadIdx.x;
    const int ty  = threadIdx.y;
    const int tz  = threadIdx.z;
    const int bx0 = blockIdx.x * TILE;
    const int by0 = blockIdx.y * TILE;
    const int b   = blockIdx.z;
    const float* __restrict__ inb = in + b * (CC * HH * WW);

    // ---- stage halo tile (reflect pad), channel-interleaved, pre-scaled ----
    const int tid = (tz * TILE + ty) * TILE + tx;
    for (int idx = tid; idx < HALO * HALO * CC; idx += NPX * ZS) {
        int c   = idx / (HALO * HALO);
        int rem = idx - c * (HALO * HALO);
        int y   = rem / HALO;
        int x   = rem - y * HALO;
        int gy  = by0 + y - PAD;
        gy = (gy < 0) ? -gy : ((gy >= HH) ? 2 * (HH - 1) - gy : gy);
        int gx  = bx0 + x - PAD;
        gx = (gx < 0) ? -gx : ((gx >= WW) ? 2 * (WW - 1) - gx : gx);
        smem[(y * HALO + x) * CC + c] = inb[(c * HH + gy) * WW + gx] * SCL;
    }
    __syncthreads();

    const float4* __restrict__ sm4 = reinterpret_cast<const float4*>(smem);
    const float4 cv = sm4[(ty + PAD) * HALO + (tx + PAD)];

    float a0 = 0.f, a1 = 0.f, a2 = 0.f, a3 = 0.f, w = 0.f;
    // balanced tap split: 43 + 43 + 43 + 40 = 169; tz is wave-uniform
    if      (tz == 0) taps<0,   43>(sm4, ty, tx, cv, a0, a1, a2, a3, w);
    else if (tz == 1) taps<43,  86>(sm4, ty, tx, cv, a0, a1, a2, a3, w);
    else if (tz == 2) taps<86, 129>(sm4, ty, tx, cv, a0, a1, a2, a3, w);
    else              taps<129,169>(sm4, ty, tx, cv, a0, a1, a2, a3, w);

    const int p = ty * TILE + tx;
    if (tz > 0) {
        float* q = &part[((tz - 1) * NPX + p) * 5];
        q[0] = a0; q[1] = a1; q[2] = a2; q[3] = a3; q[4] = w;
    }
    __syncthreads();

    if (tz == 0) {
        #pragma unroll
        for (int z = 0; z < ZS - 1; ++z) {
            const float* q = &part[(z * NPX + p) * 5];
            a0 += q[0]; a1 += q[1]; a2 += q[2]; a3 += q[3]; w += q[4];
        }
        const float inv = INV_SCL / w;
        const int gy = by0 + ty;
        const int gx = bx0 + tx;
        float* __restrict__ outb = out + b * (CC * HH * WW);
        outb[(0 * HH + gy) * WW + gx] = a0 * inv;
        outb[(1 * HH + gy) * WW + gx] = a1 * inv;
        outb[(2 * HH + gy) * WW + gx] = a2 * inv;
        outb[(3 * HH + gy) * WW + gx] = a3 * inv;
    }
}

extern "C" void kernel_launch(void* const* d_in, const int* in_sizes, int n_in,
                              void* d_out, int out_size, void* d_ws, size_t ws_size,
                              hipStream_t stream) {
    const float* x = (const float*)d_in[0];
    float* out = (float*)d_out;
    dim3 grid(WW / TILE, HH / TILE, 2);
    dim3 block(TILE, TILE, ZS);
    bilateral_kernel<<<grid, block, 0, stream>>>(x, out);
}